// Round 1
// 230.835 us; speedup vs baseline: 1.1607x; 1.1607x over previous
//
#include <hip/hip_runtime.h>
#include <hip/hip_bf16.h>

#define B_  16
#define C_  256
#define H_  48
#define W_  64
#define ND  21           // displacements per axis
#define HW  (H_ * W_)
#define CHW (C_ * H_ * W_)

typedef __attribute__((ext_vector_type(8))) short bf16x8;
typedef __attribute__((ext_vector_type(4))) float f32x4;

__device__ __forceinline__ unsigned int bf16rtne(float f) {
  unsigned int u = __builtin_bit_cast(unsigned int, f);
  return (u + 0x7fffu + ((u >> 16) & 1u)) >> 16;
}

// ---------------------------------------------------------------------------
// Kernel 1 (unchanged): fp32 NCHW -> bf16 FRAGMENT-MAJOR layout, per (b,y) row:
//   granule G = ks*256 + t16*64 + quad*16 + l15   (16B granules)
//   content  = bf16 src[x = t16*16+l15][k = ks*32+quad*8 .. +8)
// ---------------------------------------------------------------------------
__global__ __launch_bounds__(256) void transpose_cvt(
    const float* __restrict__ in1, const float* __restrict__ in2,
    unsigned short* __restrict__ o1, unsigned short* __restrict__ o2) {
  __shared__ unsigned short T[256 * 66];   // [c][x], stride 66 (odd word stride)

  int blk = blockIdx.x;
  const float* in = in1;
  unsigned short* op = o1;
  if (blk >= B_ * H_) { blk -= B_ * H_; in = in2; op = o2; }
  int y = blk % H_;
  int b = blk / H_;
  int t = threadIdx.x;

  // ---- phase 1: global fp32 -> bf16 -> LDS[c][x] ----
  int u  = t & 15;          // x-quad: x = 4u..4u+3
  int cb = t >> 4;          // c base 0..15, c = cb + 16r
  const float* src = in + (long)b * CHW + y * W_ + u * 4;
#pragma unroll
  for (int r = 0; r < 16; r++) {
    int c = cb + 16 * r;
    float4 v = *(const float4*)(src + (long)c * HW);
    unsigned int p0 = bf16rtne(v.x) | (bf16rtne(v.y) << 16);
    unsigned int p1 = bf16rtne(v.z) | (bf16rtne(v.w) << 16);
    unsigned int* Tw = (unsigned int*)(T + c * 66 + u * 4);
    Tw[0] = p0;
    Tw[1] = p1;
  }
  __syncthreads();

  // ---- phase 2: LDS gather -> fragment-major 16B stores ----
  int x   = t >> 2;         // pixel 0..63
  int cq  = t & 3;
  int t16 = x >> 4, xl = x & 15;
  unsigned short* orow = op + (long)(b * H_ + y) * (W_ * C_);
#pragma unroll
  for (int g = 0; g < 8; g++) {
    int gg = (g + cq) & 7;              // bank-spread rotation
    int kg = cq * 8 + gg;               // k-granule 0..31
    int c0 = kg * 8;                    // first channel of this granule
    unsigned int wv[4];
#pragma unroll
    for (int k2 = 0; k2 < 4; k2++) {
      unsigned int lo = T[(c0 + 2 * k2) * 66 + x];
      unsigned int hi = T[(c0 + 2 * k2 + 1) * 66 + x];
      wv[k2] = lo | (hi << 16);
    }
    int ks = kg >> 2, qd = kg & 3;
    int G = ks * 256 + t16 * 64 + qd * 16 + xl;
    *(uint4*)(orow + (long)G * 8) = *(uint4*)wv;
  }
}

// ---------------------------------------------------------------------------
// async global -> LDS, 16B per lane (wave-uniform LDS base + lane*16)
// ---------------------------------------------------------------------------
__device__ __forceinline__ void gl_lds16(const void* g, void* l) {
  __builtin_amdgcn_global_load_lds(
      (const __attribute__((address_space(1))) void*)g,
      (__attribute__((address_space(3))) void*)l, 16, 0, 0);
}

// ---------------------------------------------------------------------------
// Kernel 2: correlation v6.
//   - XCD-swizzled blockIdx (768 = 8 XCDs x 96): per-XCD B working set ~3MB
//     fits the 4MB XCD L2 (B rows reused 21x from L2 instead of IF$/HBM).
//   - B row staged to LDS once per (block,dyi) via global_load_lds width=16,
//     2-phase double buffer: stage(d+1) issued before compute(d) -> latency
//     hidden under MFMA; each wave's B-frag reads are conflict-free
//     ds_read_b128 (contiguous 1KB/wave).
//   - Epilogue: acc scattered into padded LDS slab [21][65], then written out
//     as coalesced 256B/wave rows (replaces 4B x 32-line scatter stores).
//     Edge zeros come free from the pre-zeroed slab.
// LDS = 2*32KB + 5.5KB ~= 71KB -> 2 blocks/CU.
// ---------------------------------------------------------------------------
__global__ __launch_bounds__(256, 2) void corr_kernel(
    const unsigned short* __restrict__ A2, const unsigned short* __restrict__ B2,
    float* __restrict__ out) {
  __shared__ unsigned short Bb[2][16384];   // 2 x 32KB B-row double buffer
  __shared__ float slab[ND * 65];           // [dxi][x], pad 65 (conflict-free)

  int bid = blockIdx.x;
  int blk = (bid & 7) * 96 + (bid >> 3);    // XCD swizzle, bijective (768=8*96)
  int y    = blk % H_;
  int b    = blk / H_;
  int t    = threadIdx.x;
  int lane = t & 63;
  int w    = t >> 6;
  int l15  = lane & 15;
  int quad = lane >> 4;
  int mh   = w & 1;
  int nh   = w >> 1;

  // contiguous valid-dyi range: y2 = y + 2*d - 20 in [0,H)
  int dlo = (y < 20) ? ((21 - y) >> 1) : 0;
  int dhi = (67 - y) >> 1; if (dhi > 20) dhi = 20;

  const unsigned short* browbase = B2 + (long)(b * H_) * (W_ * C_);

  // ---- prologue: issue first B-row stage ASAP ----
  {
    int y2 = y + 2 * dlo - 20;
    const unsigned short* src = browbase + (long)y2 * (W_ * C_) + lane * 8;
#pragma unroll
    for (int j = 0; j < 8; j++) {
      int c = w * 8 + j;                    // each wave stages 8 x 1KB chunks
      gl_lds16(src + c * 512, &Bb[0][c * 512]);
    }
  }

  // ---- A fragments: registers, once per block ----
  const unsigned short* rowA = A2 + (long)(b * H_ + y) * (W_ * C_);
  bf16x8 afrag[2][8];
#pragma unroll
  for (int mtl = 0; mtl < 2; mtl++) {
    int mtg = mh * 2 + mtl;
#pragma unroll
    for (int ks = 0; ks < 8; ks++)
      afrag[mtl][ks] = *(const bf16x8*)(rowA + ks * 2048 + mtg * 512 + lane * 8);
  }

  // ---- per-lane slab-scatter offsets (dyi-invariant): dxi*65 + xx, or -1 ----
  int soff[2][2][4];
#pragma unroll
  for (int mtl = 0; mtl < 2; mtl++)
#pragma unroll
    for (int ntl = 0; ntl < 2; ntl++)
#pragma unroll
      for (int r = 0; r < 4; r++) {
        int xx = (mh * 2 + mtl) * 16 + quad * 4 + r;
        int xp = (nh * 2 + ntl) * 16 + l15;
        int dx = xp - xx;
        soff[mtl][ntl][r] =
            (dx >= -20 && dx <= 20 && !(dx & 1)) ? (((dx + 20) >> 1) * 65 + xx) : -1;
      }

  // tile-pair liveness (wave-uniform): |16*(ntg-mtg)| <= 35
  bool live[2][2];
#pragma unroll
  for (int mtl = 0; mtl < 2; mtl++)
#pragma unroll
    for (int ntl = 0; ntl < 2; ntl++) {
      int diff = (nh * 2 + ntl) - (mh * 2 + mtl);
      live[mtl][ntl] = (diff >= -2 && diff <= 2);
    }

  float* ob = out + (long)b * (ND * ND * HW) + y * W_;

  // ---- zero planes for out-of-range dyi (coalesced; overlaps first stage) ----
  for (int d = 0; d < dlo; d++) {
    float* od = ob + (long)d * (ND * HW);
    for (int i = t; i < ND * W_; i += 256) od[(i >> 6) * HW + (i & 63)] = 0.0f;
  }
  for (int d = dhi + 1; d < ND; d++) {
    float* od = ob + (long)d * (ND * HW);
    for (int i = t; i < ND * W_; i += 256) od[(i >> 6) * HW + (i & 63)] = 0.0f;
  }

  // ---- slab zero-init ----
  for (int i = t; i < ND * 65; i += 256) slab[i] = 0.0f;

  __syncthreads();   // drains prologue stage (vmcnt) + slab init

  int cur = 0;
  for (int d = dlo; d <= dhi; d++) {
    float* od = ob + (long)d * (ND * HW);

    // ---- issue next dyi's B-row stage into the other buffer ----
    if (d < dhi) {
      int y2n = y + 2 * (d + 1) - 20;
      const unsigned short* src = browbase + (long)y2n * (W_ * C_) + lane * 8;
#pragma unroll
      for (int j = 0; j < 8; j++) {
        int c = w * 8 + j;
        gl_lds16(src + c * 512, &Bb[cur ^ 1][c * 512]);
      }
    }

    // ---- compute from Bb[cur]: conflict-free ds_read_b128 + MFMA ----
    const unsigned short* lb = &Bb[cur][0];
    f32x4 acc[2][2];
#pragma unroll
    for (int mtl = 0; mtl < 2; mtl++)
#pragma unroll
      for (int ntl = 0; ntl < 2; ntl++) acc[mtl][ntl] = (f32x4){0.f, 0.f, 0.f, 0.f};

#pragma unroll
    for (int ks = 0; ks < 8; ks++) {
      bf16x8 b0 = *(const bf16x8*)(lb + ks * 2048 + (nh * 2 + 0) * 512 + lane * 8);
      bf16x8 b1 = *(const bf16x8*)(lb + ks * 2048 + (nh * 2 + 1) * 512 + lane * 8);
#pragma unroll
      for (int mtl = 0; mtl < 2; mtl++) {
        if (live[mtl][0])
          acc[mtl][0] = __builtin_amdgcn_mfma_f32_16x16x32_bf16(afrag[mtl][ks], b0,
                                                                acc[mtl][0], 0, 0, 0);
        if (live[mtl][1])
          acc[mtl][1] = __builtin_amdgcn_mfma_f32_16x16x32_bf16(afrag[mtl][ks], b1,
                                                                acc[mtl][1], 0, 0, 0);
      }
    }

    // ---- band-extract scatter into LDS slab ----
#pragma unroll
    for (int mtl = 0; mtl < 2; mtl++)
#pragma unroll
      for (int ntl = 0; ntl < 2; ntl++)
#pragma unroll
        for (int r = 0; r < 4; r++) {
          int so = soff[mtl][ntl][r];
          if (so >= 0) slab[so] = acc[mtl][ntl][r] * (1.0f / 256.0f);
        }

    __syncthreads();   // scatter done (also drains next stage's vmcnt)

    // ---- coalesced store (256B/wave rows) + slab rezero ----
    for (int i = t; i < ND * W_; i += 256) {
      int dxi = i >> 6, x = i & 63;
      od[dxi * HW + x] = slab[dxi * 65 + x];
      slab[dxi * 65 + x] = 0.0f;
    }

    __syncthreads();   // slab clean + Bb[cur] reads done before restage
    cur ^= 1;
  }
}

// ---------------------------------------------------------------------------
extern "C" void kernel_launch(void* const* d_in, const int* in_sizes, int n_in,
                              void* d_out, int out_size, void* d_ws, size_t ws_size,
                              hipStream_t stream) {
  (void)in_sizes; (void)n_in; (void)out_size; (void)ws_size;
  const float* in1 = (const float*)d_in[0];
  const float* in2 = (const float*)d_in[1];
  float* out = (float*)d_out;

  unsigned short* o1 = (unsigned short*)d_ws;                    // bf16 frag-major
  unsigned short* o2 = o1 + (size_t)B_ * H_ * W_ * C_;           // bf16 frag-major

  transpose_cvt<<<2 * B_ * H_, 256, 0, stream>>>(in1, in2, o1, o2);
  corr_kernel<<<B_ * H_, 256, 0, stream>>>(o1, o2, out);
}